// Round 3
// baseline (141.398 us; speedup 1.0000x reference)
//
#include <hip/hip_runtime.h>

#define HW    4096
#define CDIM  64
#define KCB   1024
#define NELM  8388608
#define NBLK  1024

typedef __attribute__((ext_vector_type(8))) short  short8;
typedef __attribute__((ext_vector_type(4))) float  float4v;

__device__ inline unsigned short f2bf(float v) {
    unsigned u = __builtin_bit_cast(unsigned, v);
    unsigned r = u + 0x7FFF + ((u >> 16) & 1);   // RNE
    return (unsigned short)(r >> 16);
}
__device__ inline unsigned umin32(unsigned a, unsigned b) { return a < b ? a : b; }

// ws: [0..1023] e_sq+1.0 fp32, [1024] loss accum, [1025] ticket, [2048..] bf16 cbB (frag order)
__global__ void vq_prep(const float* __restrict__ cb, float* __restrict__ esqb,
                        float* __restrict__ accum, int* __restrict__ cnt,
                        unsigned short* __restrict__ cbB) {
    int u = blockIdx.x * 256 + threadIdx.x;      // 0..8191
    if (u == 0) { *accum = 0.0f; *cnt = 0; }
    if (u < KCB) {
        const float* row = cb + u * CDIM;
        float s = 0.0f;
        #pragma unroll
        for (int c = 0; c < CDIM; ++c) s = fmaf(row[c], row[c], s);
        esqb[u] = s + 1.0f;                      // +1 bias => distances strictly positive
    }
    // B-frag order: element index = kt*128 + f*64 + q*16 + n   (units of short8)
    int k = u >> 3, s7 = u & 7;
    const float* src = cb + k * CDIM + s7 * 8;
    unsigned short tmp[8];
    #pragma unroll
    for (int j = 0; j < 8; ++j) tmp[j] = f2bf(src[j]);
    int t = k >> 4, n = k & 15, f = s7 >> 2, q = s7 & 3;
    int dst = (((t * 2 + f) * 64) + q * 16 + n) * 8;
    *(short8*)(cbB + dst) = *(short8*)tmp;
}

__global__ __launch_bounds__(256)
void vq_main(const float* __restrict__ x,
             const float* __restrict__ cb,
             const float* __restrict__ esqb,
             const unsigned short* __restrict__ cbB,
             float* __restrict__ zq,
             float* __restrict__ accum,
             int* __restrict__ cnt,
             float* __restrict__ loss_out) {
    __shared__ unsigned short abf[128 * 72];     // -2x bf16, A-frag layout, stride 72
    __shared__ unsigned short bbuf[2][8192];     // 8 k-tiles/chunk, double buffered (2x16KB)
    __shared__ float xsqp[256];
    __shared__ float dbl[128];
    __shared__ int   idxl[128];
    __shared__ float part[2];

    const int t   = threadIdx.x;
    const int n0  = blockIdx.x * 128;
    const int b   = n0 >> 12;
    const int hw0 = n0 & (HW - 1);
    const int l   = t & 63, w = t >> 6;
    const int col = l & 15, q = l >> 4;

    // async copy of one 16KB chunk (8 k-tiles) of cbB into LDS: 16 segments of 1KB
    auto issue_chunk = [&](int c) {
        const unsigned short* gbase = cbB + c * 8192;
        unsigned short*       lbase = &bbuf[c & 1][0];
        #pragma unroll
        for (int i = 0; i < 4; ++i) {
            int s = w * 4 + i;
            __builtin_amdgcn_global_load_lds(
                (const __attribute__((address_space(1))) unsigned int*)(gbase + s * 512 + l * 8),
                (__attribute__((address_space(3))) unsigned int*)(lbase + s * 512),
                16, 0, 0);
        }
    };

    issue_chunk(0);   // in flight during x staging

    // ---- stage x: thread t handles point p, channel half cg ----
    {
        const int p = t & 127, cg = t >> 7;
        const float* xp = x + ((size_t)b * CDIM + cg * 32) * HW + hw0 + p;
        float xs = 0.0f;
        #pragma unroll
        for (int j = 0; j < 32; j += 2) {
            float v0 = xp[(size_t)j * HW];
            float v1 = xp[(size_t)(j + 1) * HW];
            xs = fmaf(v0, v0, xs);
            xs = fmaf(v1, v1, xs);
            unsigned pk = (unsigned)f2bf(-2.0f * v0) | ((unsigned)f2bf(-2.0f * v1) << 16);
            *(unsigned*)&abf[p * 72 + cg * 32 + j] = pk;
        }
        xsqp[cg * 128 + p] = xs;
    }
    __syncthreads();   // abf ready AND chunk 0 resident (vmcnt drained by barrier)

    // ---- A fragments: wave w owns points w*32..w*32+31 ----
    short8 a[2][2];
    #pragma unroll
    for (int mt = 0; mt < 2; ++mt)
        #pragma unroll
        for (int f = 0; f < 2; ++f)
            a[mt][f] = *(const short8*)&abf[(w * 32 + mt * 16 + col) * 72 + f * 32 + q * 8];

    // ---- k-loop over 8 chunks x 8 k-tiles; packed argmin ----
    unsigned bm[8];
    #pragma unroll
    for (int i = 0; i < 8; ++i) bm[i] = 0xFFFFFFFFu;
    unsigned cand = (unsigned)col;               // becomes kt*16+col

    for (int c = 0; c < 8; ++c) {
        if (c) __syncthreads();                  // chunk c resident; buf (c+1)&1 free
        if (c + 1 < 8) issue_chunk(c + 1);
        const unsigned short* bb = &bbuf[c & 1][0];
        #pragma unroll
        for (int j = 0; j < 8; ++j) {
            int kt = c * 8 + j;
            short8 b0 = *(const short8*)&bb[(j * 128 + l) * 8];
            short8 b1 = *(const short8*)&bb[(j * 128 + 64 + l) * 8];
            float  ev = esqb[kt * 16 + col];
            float4v c0 = {ev, ev, ev, ev};
            float4v acc0 = __builtin_amdgcn_mfma_f32_16x16x32_bf16(a[0][0], b0, c0, 0, 0, 0);
            acc0 = __builtin_amdgcn_mfma_f32_16x16x32_bf16(a[0][1], b1, acc0, 0, 0, 0);
            float4v acc1 = __builtin_amdgcn_mfma_f32_16x16x32_bf16(a[1][0], b0, c0, 0, 0, 0);
            acc1 = __builtin_amdgcn_mfma_f32_16x16x32_bf16(a[1][1], b1, acc1, 0, 0, 0);
            #pragma unroll
            for (int r = 0; r < 4; ++r) {
                unsigned p0 = (__builtin_bit_cast(unsigned, acc0[r]) & 0xFFFFFC00u) | cand;
                unsigned p1 = (__builtin_bit_cast(unsigned, acc1[r]) & 0xFFFFFC00u) | cand;
                bm[r]     = umin32(bm[r], p0);
                bm[4 + r] = umin32(bm[4 + r], p1);
            }
            cand += 16;
        }
    }

    // ---- argmin across 16 code-columns (packed butterfly) ----
    #pragma unroll
    for (int s = 1; s < 16; s <<= 1)
        #pragma unroll
        for (int i = 0; i < 8; ++i) {
            unsigned o = (unsigned)__shfl_xor((int)bm[i], s, 64);
            bm[i] = umin32(bm[i], o);
        }
    if (col == 0) {
        #pragma unroll
        for (int mt = 0; mt < 2; ++mt)
            #pragma unroll
            for (int r = 0; r < 4; ++r) {
                int p = w * 32 + mt * 16 + q * 4 + r;
                unsigned v = bm[mt * 4 + r];
                dbl[p]  = __builtin_bit_cast(float, v & 0xFFFFFC00u) - 1.0f; // un-bias
                idxl[p] = (int)(v & 1023u);
            }
    }
    __syncthreads();

    // ---- loss: per-point  x_sq + best(e_sq - 2 dot) ----
    if (t < 128) {
        float lp = dbl[t] + xsqp[t] + xsqp[128 + t];
        #pragma unroll
        for (int off = 32; off > 0; off >>= 1) lp += __shfl_down(lp, off, 64);
        if ((t & 63) == 0) part[t >> 6] = lp;
    }
    __syncthreads();

    // ---- fused final: last block writes the loss ----
    if (t == 0) {
        atomicAdd(accum, part[0] + part[1]);
        __threadfence();
        int tk = atomicAdd(cnt, 1);
        if (tk == NBLK - 1) {
            float tot = atomicAdd(accum, 0.0f);   // all adds visible (ticket + fences)
            loss_out[0] = 1.25f * tot * (1.0f / (float)NELM);
        }
    }

    // ---- z_q: gather winning rows (L1/L2-hot), coalesced strided store ----
    {
        const int p = t & 127, ch = t >> 7;
        const float4v* crow = (const float4v*)(cb + (size_t)idxl[p] * CDIM + ch * 32);
        float* zp = zq + ((size_t)b * CDIM + ch * 32) * HW + hw0 + p;
        #pragma unroll
        for (int i = 0; i < 8; ++i) {
            float4v vv = crow[i];
            zp[(size_t)(i * 4 + 0) * HW] = vv[0];
            zp[(size_t)(i * 4 + 1) * HW] = vv[1];
            zp[(size_t)(i * 4 + 2) * HW] = vv[2];
            zp[(size_t)(i * 4 + 3) * HW] = vv[3];
        }
    }
}

extern "C" void kernel_launch(void* const* d_in, const int* in_sizes, int n_in,
                              void* d_out, int out_size, void* d_ws, size_t ws_size,
                              hipStream_t stream) {
    const float* x  = (const float*)d_in[0];
    const float* cb = (const float*)d_in[1];
    float* esqb  = (float*)d_ws;                         // 1024 floats (biased +1)
    float* accum = esqb + KCB;                           // 1 float
    int*   cnt   = (int*)(esqb + KCB + 1);               // 1 int
    unsigned short* cbB = (unsigned short*)(esqb + 2048); // 128 KB bf16, frag order
    float* zq   = (float*)d_out;
    float* loss = zq + NELM;

    vq_prep <<<32,   256, 0, stream>>>(cb, esqb, accum, cnt, cbB);
    vq_main <<<NBLK, 256, 0, stream>>>(x, cb, esqb, cbB, zq, accum, cnt, loss);
}

// Round 4
// 136.626 us; speedup vs baseline: 1.0349x; 1.0349x over previous
//
#include <hip/hip_runtime.h>

#define HW    4096
#define CDIM  64
#define KCB   1024
#define NELM  8388608
#define NBLK  512

typedef __attribute__((ext_vector_type(8))) short  short8;
typedef __attribute__((ext_vector_type(4))) float  float4v;

__device__ inline unsigned short f2bf(float v) {
    unsigned u = __builtin_bit_cast(unsigned, v);
    unsigned r = u + 0x7FFF + ((u >> 16) & 1);   // RNE
    return (unsigned short)(r >> 16);
}
__device__ inline unsigned umin32(unsigned a, unsigned b) { return a < b ? a : b; }

// ws: [0..1023] e_sq+1.0 fp32 | [1024] loss accum | [1025] ticket | [2048..] bf16 -2*cb (B-frag order)
__global__ void vq_prep(const float* __restrict__ cb, float* __restrict__ esqb,
                        float* __restrict__ accum, int* __restrict__ cnt,
                        unsigned short* __restrict__ cbB) {
    int u = blockIdx.x * 256 + threadIdx.x;      // 0..8191
    if (u == 0) { *accum = 0.0f; *cnt = 0; }
    if (u < KCB) {
        const float* row = cb + u * CDIM;
        float s = 0.0f;
        #pragma unroll
        for (int c = 0; c < CDIM; ++c) s = fmaf(row[c], row[c], s);
        esqb[u] = s + 1.0f;                      // +1 bias => packed distances strictly positive
    }
    // B-frag order (R2-verified): lane l of k-tile kt, frag f reads element (kt*128 + f*64 + l) [short8]
    // B now carries -2*e (exact doubling; A carries raw x).
    int k = u >> 3, s7 = u & 7;                  // code, 8-channel segment
    const float* src = cb + k * CDIM + s7 * 8;
    unsigned short tmp[8];
    #pragma unroll
    for (int j = 0; j < 8; ++j) tmp[j] = f2bf(-2.0f * src[j]);
    int kt = k >> 4, n = k & 15, f = s7 >> 2, q = s7 & 3;
    int dst = (((kt * 2 + f) * 64) + q * 16 + n) * 8;
    *(short8*)(cbB + dst) = *(short8*)tmp;
}

__global__ __launch_bounds__(256)
void vq_main(const float* __restrict__ x,
             const float* __restrict__ cb,
             const float* __restrict__ esqb,
             const unsigned short* __restrict__ cbB,
             float* __restrict__ zq,
             float* __restrict__ accum,
             int* __restrict__ cnt,
             float* __restrict__ loss_out) {
    __shared__ float lesq[KCB];     // 4 KB
    __shared__ int   idxl[256];     // 1 KB

    const int t   = threadIdx.x;
    const int n0  = blockIdx.x * 256;            // 256 points per block
    const int b   = n0 >> 12;
    const int hw0 = n0 & (HW - 1);
    const int l   = t & 63, w = t >> 6;
    const int col = l & 15, q = l >> 4;
    const int p0  = w * 64;                      // wave's first point in block

    // stage e_sq into LDS (broadcast-read later; conflict-free)
    #pragma unroll
    for (int i = 0; i < 4; ++i) lesq[i * 256 + t] = esqb[i * 256 + t];

    // ---- A fragments direct from global: lane l holds A[m=col][k=q*8+j], 4 m-tiles ----
    short8 a[4][2];
    float  xs = 0.0f;                            // exact sum of x^2 over this lane's elements
    const float* xbase = x + (size_t)b * CDIM * HW + hw0;
    #pragma unroll
    for (int mt = 0; mt < 4; ++mt) {
        const int p = p0 + mt * 16 + col;
        #pragma unroll
        for (int f = 0; f < 2; ++f) {
            unsigned short tmp[8];
            #pragma unroll
            for (int j = 0; j < 8; ++j) {
                float v = xbase[(size_t)(f * 32 + q * 8 + j) * HW + p];
                xs = fmaf(v, v, xs);
                tmp[j] = f2bf(v);
            }
            a[mt][f] = *(short8*)tmp;
        }
    }
    __syncthreads();   // lesq ready (the only barrier before the epilogue)

    // ---- k-loop: acc = (1+e_sq) + x·(-2e); packed argmin; depth-2 B prefetch ----
    unsigned bm[16];
    #pragma unroll
    for (int i = 0; i < 16; ++i) bm[i] = 0xFFFFFFFFu;
    unsigned cand = (unsigned)col;

    const short8* bp = ((const short8*)cbB) + l;
    short8 f0[2], f1[2];
    f0[0] = bp[0];   f1[0] = bp[64];
    f0[1] = bp[128]; f1[1] = bp[192];

    #pragma unroll 2
    for (int kt = 0; kt < 64; ++kt) {
        short8 b0 = f0[kt & 1], b1 = f1[kt & 1];
        if (kt < 62) {
            f0[kt & 1] = bp[(kt + 2) * 128];
            f1[kt & 1] = bp[(kt + 2) * 128 + 64];
        }
        float ev = lesq[kt * 16 + col];
        float4v c0 = {ev, ev, ev, ev};
        #pragma unroll
        for (int mt = 0; mt < 4; ++mt) {
            float4v acc = __builtin_amdgcn_mfma_f32_16x16x32_bf16(a[mt][0], b0, c0, 0, 0, 0);
            acc = __builtin_amdgcn_mfma_f32_16x16x32_bf16(a[mt][1], b1, acc, 0, 0, 0);
            #pragma unroll
            for (int r = 0; r < 4; ++r) {
                unsigned pk = (__builtin_bit_cast(unsigned, acc[r]) & 0xFFFFFC00u) | cand;
                bm[mt * 4 + r] = umin32(bm[mt * 4 + r], pk);
            }
        }
        cand += 16;
    }

    // ---- argmin across the 16 code-columns (packed butterfly over col bits) ----
    #pragma unroll
    for (int s = 1; s < 16; s <<= 1)
        #pragma unroll
        for (int i = 0; i < 16; ++i) {
            unsigned o = (unsigned)__shfl_xor((int)bm[i], s, 64);
            bm[i] = umin32(bm[i], o);
        }

    // publish indices: point = p0 + mt*16 + q*4 + r  (D row = q*4+r)
    if (col == 0) {
        #pragma unroll
        for (int mt = 0; mt < 4; ++mt)
            #pragma unroll
            for (int r = 0; r < 4; ++r)
                idxl[p0 + mt * 16 + q * 4 + r] = (int)(bm[mt * 4 + r] & 1023u);
    }

    // ---- loss: wave-exact  Σ x_sq + Σ best(e_sq - 2 dot) ----
    {
        float dsum = 0.0f;
        #pragma unroll
        for (int i = 0; i < 16; ++i)
            dsum += __builtin_bit_cast(float, bm[i] & 0xFFFFFC00u);
        // d replicated over 16 col-lanes -> /16; bias (+1 per point) -> -1 per lane after /16
        float lp = xs + dsum * 0.0625f - 1.0f;
        #pragma unroll
        for (int off = 32; off > 0; off >>= 1) lp += __shfl_down(lp, off, 64);
        if (l == 0) atomicAdd(accum, lp);
    }
    __syncthreads();   // idxl ready

    // ---- fused final: last block writes the loss ----
    if (t == 0) {
        __threadfence();
        int tk = atomicAdd(cnt, 1);
        if (tk == NBLK - 1) {
            float tot = atomicAdd(accum, 0.0f);
            loss_out[0] = 1.25f * tot * (1.0f / (float)NELM);
        }
    }

    // ---- z_q: gather winning rows (L2-hot), coalesced strided stores ----
    {
        const float4v* crow = (const float4v*)(cb + (size_t)idxl[t] * CDIM);
        float* zp = zq + (size_t)b * CDIM * HW + hw0 + t;
        #pragma unroll
        for (int i = 0; i < 16; ++i) {
            float4v vv = crow[i];
            zp[(size_t)(i * 4 + 0) * HW] = vv[0];
            zp[(size_t)(i * 4 + 1) * HW] = vv[1];
            zp[(size_t)(i * 4 + 2) * HW] = vv[2];
            zp[(size_t)(i * 4 + 3) * HW] = vv[3];
        }
    }
}

extern "C" void kernel_launch(void* const* d_in, const int* in_sizes, int n_in,
                              void* d_out, int out_size, void* d_ws, size_t ws_size,
                              hipStream_t stream) {
    const float* x  = (const float*)d_in[0];
    const float* cb = (const float*)d_in[1];
    float* esqb  = (float*)d_ws;
    float* accum = esqb + KCB;
    int*   cnt   = (int*)(esqb + KCB + 1);
    unsigned short* cbB = (unsigned short*)(esqb + 2048);
    float* zq   = (float*)d_out;
    float* loss = zq + NELM;

    vq_prep <<<32,   256, 0, stream>>>(cb, esqb, accum, cnt, cbB);
    vq_main <<<NBLK, 256, 0, stream>>>(x, cb, esqb, cbB, zq, accum, cnt, loss);
}

// Round 5
// 134.285 us; speedup vs baseline: 1.0530x; 1.0174x over previous
//
#include <hip/hip_runtime.h>

#define HW    4096
#define CDIM  64
#define KCB   1024
#define NELM  8388608
#define NBLK  512

typedef __attribute__((ext_vector_type(8))) short  short8;
typedef __attribute__((ext_vector_type(4))) float  float4v;

__device__ inline unsigned short f2bf(float v) {
    unsigned u = __builtin_bit_cast(unsigned, v);
    unsigned r = u + 0x7FFF + ((u >> 16) & 1);   // RNE
    return (unsigned short)(r >> 16);
}
__device__ inline unsigned umin32(unsigned a, unsigned b) { return a < b ? a : b; }

// ws: [0..1023] e_sq+1.0 fp32 | [1024] loss accum | [1025] ticket | [2048..] bf16 -2*cb (B-frag order)
__global__ void vq_prep(const float* __restrict__ cb, float* __restrict__ esqb,
                        float* __restrict__ accum, int* __restrict__ cnt,
                        unsigned short* __restrict__ cbB) {
    int u = blockIdx.x * 256 + threadIdx.x;      // 0..8191
    if (u == 0) { *accum = 0.0f; *cnt = 0; }
    if (u < KCB) {
        const float* row = cb + u * CDIM;
        float s = 0.0f;
        #pragma unroll
        for (int c = 0; c < CDIM; ++c) s = fmaf(row[c], row[c], s);
        esqb[u] = s + 1.0f;                      // +1 bias => packed distances strictly positive
    }
    // B-frag order (R2/R4-verified). B carries -2*e (exact doubling; A carries raw x).
    int k = u >> 3, s7 = u & 7;                  // code, 8-channel segment
    const float* src = cb + k * CDIM + s7 * 8;
    unsigned short tmp[8];
    #pragma unroll
    for (int j = 0; j < 8; ++j) tmp[j] = f2bf(-2.0f * src[j]);
    int kt = k >> 4, n = k & 15, f = s7 >> 2, q = s7 & 3;
    int dst = (((kt * 2 + f) * 64) + q * 16 + n) * 8;
    *(short8*)(cbB + dst) = *(short8*)tmp;
}

__global__ __launch_bounds__(256, 2)   // 2 waves/SIMD: VGPR cap 256 -> no scratch spills
void vq_main(const float* __restrict__ x,
             const float* __restrict__ cb,
             const float* __restrict__ esqb,
             const unsigned short* __restrict__ cbB,
             float* __restrict__ zq,
             float* __restrict__ accum,
             int* __restrict__ cnt,
             float* __restrict__ loss_out) {
    __shared__ float lesq[KCB];     // 4 KB
    __shared__ int   idxl[256];     // 1 KB

    const int t   = threadIdx.x;
    const int n0  = blockIdx.x * 256;            // 256 points per block
    const int b   = n0 >> 12;
    const int hw0 = n0 & (HW - 1);
    const int l   = t & 63, w = t >> 6;
    const int col = l & 15, q = l >> 4;
    const int p0  = w * 64;                      // wave's first point in block

    // stage e_sq into LDS (broadcast-friendly, conflict-free reads later)
    #pragma unroll
    for (int i = 0; i < 4; ++i) lesq[i * 256 + t] = esqb[i * 256 + t];

    // ---- A fragments direct from global: lane l holds A[m=col][k=q*8+j], 4 m-tiles ----
    short8 a[4][2];
    float  xs = 0.0f;                            // exact per-lane sum of x^2
    const float* xbase = x + (size_t)b * CDIM * HW + hw0;
    #pragma unroll
    for (int mt = 0; mt < 4; ++mt) {
        const int p = p0 + mt * 16 + col;
        #pragma unroll
        for (int f = 0; f < 2; ++f) {
            unsigned short tmp[8];
            #pragma unroll
            for (int j = 0; j < 8; ++j) {
                float v = xbase[(size_t)(f * 32 + q * 8 + j) * HW + p];
                xs = fmaf(v, v, xs);
                tmp[j] = f2bf(v);
            }
            a[mt][f] = *(short8*)tmp;
        }
    }
    __syncthreads();   // lesq ready

    // ---- k-loop: acc = (1+e_sq) + x·(-2e); packed argmin ----
    unsigned bm[16];
    #pragma unroll
    for (int i = 0; i < 16; ++i) bm[i] = 0xFFFFFFFFu;
    unsigned cand = (unsigned)col;

    const short8* bp = ((const short8*)cbB) + l;

    auto kt_body = [&](int kt, short8 b0, short8 b1) {
        float ev = lesq[kt * 16 + col];
        float4v c0 = {ev, ev, ev, ev};
        #pragma unroll
        for (int mt = 0; mt < 4; ++mt) {
            float4v acc = __builtin_amdgcn_mfma_f32_16x16x32_bf16(a[mt][0], b0, c0, 0, 0, 0);
            acc = __builtin_amdgcn_mfma_f32_16x16x32_bf16(a[mt][1], b1, acc, 0, 0, 0);
            #pragma unroll
            for (int r = 0; r < 4; ++r) {
                unsigned pk = (__builtin_bit_cast(unsigned, acc[r]) & 0xFFFFFC00u) | cand;
                bm[mt * 4 + r] = umin32(bm[mt * 4 + r], pk);
            }
        }
        cand += 16;
    };

    // two named prefetch slots (no arrays -> no scratch), distance = 4 k-tiles
    short8 A0 = bp[0 * 128], A1 = bp[0 * 128 + 64];
    short8 A2 = bp[1 * 128], A3 = bp[1 * 128 + 64];
    short8 B0 = bp[2 * 128], B1 = bp[2 * 128 + 64];
    short8 B2 = bp[3 * 128], B3 = bp[3 * 128 + 64];

    for (int kt = 0; kt < 64; kt += 4) {
        short8 t0 = A0, t1 = A1, t2 = A2, t3 = A3;
        if (kt + 4 < 64) {
            A0 = bp[(kt + 4) * 128]; A1 = bp[(kt + 4) * 128 + 64];
            A2 = bp[(kt + 5) * 128]; A3 = bp[(kt + 5) * 128 + 64];
        }
        kt_body(kt,     t0, t1);
        kt_body(kt + 1, t2, t3);
        short8 u0 = B0, u1 = B1, u2 = B2, u3 = B3;
        if (kt + 6 < 64) {
            B0 = bp[(kt + 6) * 128]; B1 = bp[(kt + 6) * 128 + 64];
            B2 = bp[(kt + 7) * 128]; B3 = bp[(kt + 7) * 128 + 64];
        }
        kt_body(kt + 2, u0, u1);
        kt_body(kt + 3, u2, u3);
    }

    // ---- argmin across the 16 code-columns (packed butterfly) ----
    #pragma unroll
    for (int s = 1; s < 16; s <<= 1)
        #pragma unroll
        for (int i = 0; i < 16; ++i) {
            unsigned o = (unsigned)__shfl_xor((int)bm[i], s, 64);
            bm[i] = umin32(bm[i], o);
        }

    // publish indices: point = p0 + mt*16 + q*4 + r
    if (col == 0) {
        #pragma unroll
        for (int mt = 0; mt < 4; ++mt)
            #pragma unroll
            for (int r = 0; r < 4; ++r)
                idxl[p0 + mt * 16 + q * 4 + r] = (int)(bm[mt * 4 + r] & 1023u);
    }

    // ---- loss: wave-exact  Σ x_sq + Σ best(e_sq - 2 dot) ----
    {
        float dsum = 0.0f;
        #pragma unroll
        for (int i = 0; i < 16; ++i)
            dsum += __builtin_bit_cast(float, bm[i] & 0xFFFFFC00u);
        float lp = xs + dsum * 0.0625f - 1.0f;   // /16 col-replication; un-bias
        #pragma unroll
        for (int off = 32; off > 0; off >>= 1) lp += __shfl_down(lp, off, 64);
        if (l == 0) atomicAdd(accum, lp);
    }
    __syncthreads();   // idxl ready

    // ---- fused final: last block writes the loss ----
    if (t == 0) {
        __threadfence();
        int tk = atomicAdd(cnt, 1);
        if (tk == NBLK - 1) {
            float tot = atomicAdd(accum, 0.0f);
            loss_out[0] = 1.25f * tot * (1.0f / (float)NELM);
        }
    }

    // ---- z_q: gather winning rows (L2-hot), coalesced strided stores ----
    {
        const float4v* crow = (const float4v*)(cb + (size_t)idxl[t] * CDIM);
        float* zp = zq + (size_t)b * CDIM * HW + hw0 + t;
        #pragma unroll
        for (int i = 0; i < 16; ++i) {
            float4v vv = crow[i];
            zp[(size_t)(i * 4 + 0) * HW] = vv[0];
            zp[(size_t)(i * 4 + 1) * HW] = vv[1];
            zp[(size_t)(i * 4 + 2) * HW] = vv[2];
            zp[(size_t)(i * 4 + 3) * HW] = vv[3];
        }
    }
}

extern "C" void kernel_launch(void* const* d_in, const int* in_sizes, int n_in,
                              void* d_out, int out_size, void* d_ws, size_t ws_size,
                              hipStream_t stream) {
    const float* x  = (const float*)d_in[0];
    const float* cb = (const float*)d_in[1];
    float* esqb  = (float*)d_ws;
    float* accum = esqb + KCB;
    int*   cnt   = (int*)(esqb + KCB + 1);
    unsigned short* cbB = (unsigned short*)(esqb + 2048);
    float* zq   = (float*)d_out;
    float* loss = zq + NELM;

    vq_prep <<<32,   256, 0, stream>>>(cb, esqb, accum, cnt, cbB);
    vq_main <<<NBLK, 256, 0, stream>>>(x, cb, esqb, cbB, zq, accum, cnt, loss);
}

// Round 6
// 128.792 us; speedup vs baseline: 1.0979x; 1.0427x over previous
//
#include <hip/hip_runtime.h>

#define HW    4096
#define CDIM  64
#define KCB   1024
#define NELM  8388608
#define NBLK  256          // one block per CU

typedef __attribute__((ext_vector_type(8))) short  short8;
typedef __attribute__((ext_vector_type(4))) float  float4v;

__device__ inline unsigned short f2bf(float v) {
    unsigned u = __builtin_bit_cast(unsigned, v);
    unsigned r = u + 0x7FFF + ((u >> 16) & 1);   // RNE
    return (unsigned short)(r >> 16);
}
__device__ inline unsigned umin32(unsigned a, unsigned b) { return a < b ? a : b; }

// ws: [0..1023] e_sq+1.0 fp32 | [1024] loss accum | [1025] ticket | [2048..] bf16 -2*cb (B-frag order)
__global__ void vq_prep(const float* __restrict__ cb, float* __restrict__ esqb,
                        float* __restrict__ accum, int* __restrict__ cnt,
                        unsigned short* __restrict__ cbB) {
    int u = blockIdx.x * 256 + threadIdx.x;      // 0..8191
    if (u == 0) { *accum = 0.0f; *cnt = 0; }
    if (u < KCB) {
        const float* row = cb + u * CDIM;
        float s = 0.0f;
        #pragma unroll
        for (int c = 0; c < CDIM; ++c) s = fmaf(row[c], row[c], s);
        esqb[u] = s + 1.0f;                      // +1 bias => packed distances strictly positive
    }
    // B-frag order (R2/R4/R5-verified). B carries -2*e (exact doubling; A carries raw x).
    int k = u >> 3, s7 = u & 7;                  // code, 8-channel segment
    const float* src = cb + k * CDIM + s7 * 8;
    unsigned short tmp[8];
    #pragma unroll
    for (int j = 0; j < 8; ++j) tmp[j] = f2bf(-2.0f * src[j]);
    int kt = k >> 4, n = k & 15, f = s7 >> 2, q = s7 & 3;
    int dst = (((kt * 2 + f) * 64) + q * 16 + n) * 8;
    *(short8*)(cbB + dst) = *(short8*)tmp;
}

__global__ __launch_bounds__(512, 2)
void vq_main(const float* __restrict__ x,
             const float* __restrict__ cb,
             const float* __restrict__ esqb,
             const unsigned short* __restrict__ cbB,
             float* __restrict__ zq,
             float* __restrict__ accum,
             int* __restrict__ cnt,
             float* __restrict__ loss_out) {
    // 137 KB static LDS: legal on gfx950 (160 KiB/CU); forces (and wants) 1 block/CU
    __shared__ unsigned short bbuf[KCB * CDIM];  // 128 KB: full bf16 -2*codebook, frag order
    __shared__ float lesq[KCB];                  // 4 KB
    __shared__ int   idxl[512];                  // 2 KB

    const int t   = threadIdx.x;                 // 0..511, 8 waves
    const int n0  = blockIdx.x * 512;            // 512 points per block
    const int b   = n0 >> 12;
    const int hw0 = n0 & (HW - 1);
    const int l   = t & 63, w = t >> 6;
    const int col = l & 15, q = l >> 4;
    const int p0  = w * 64;                      // wave's first point in block

    // ---- stage full codebook into LDS: one copy per BLOCK (not per wave) ----
    #pragma unroll
    for (int i = 0; i < 16; ++i) {
        int off = (i * 512 + t) * 8;             // shorts; 16 B per thread, wave-contiguous
        __builtin_amdgcn_global_load_lds(
            (const __attribute__((address_space(1))) unsigned int*)(cbB + off),
            (__attribute__((address_space(3))) unsigned int*)(&bbuf[off]),
            16, 0, 0);
    }
    #pragma unroll
    for (int i = 0; i < 2; ++i) lesq[i * 512 + t] = esqb[i * 512 + t];

    // ---- A fragments direct from global (overlaps cbB staging) ----
    short8 a[4][2];
    float  xs = 0.0f;                            // exact per-lane sum of x^2
    const float* xbase = x + (size_t)b * CDIM * HW + hw0;
    #pragma unroll
    for (int mt = 0; mt < 4; ++mt) {
        const int p = p0 + mt * 16 + col;
        #pragma unroll
        for (int f = 0; f < 2; ++f) {
            unsigned short tmp[8];
            #pragma unroll
            for (int j = 0; j < 8; ++j) {
                float v = xbase[(size_t)(f * 32 + q * 8 + j) * HW + p];
                xs = fmaf(v, v, xs);
                tmp[j] = f2bf(v);
            }
            a[mt][f] = *(short8*)tmp;
        }
    }
    __syncthreads();   // cbB + lesq resident; the only pre-epilogue barrier

    // ---- k-loop: all B from LDS; acc = (1+e_sq) + x·(-2e); packed argmin ----
    unsigned bm[16];
    #pragma unroll
    for (int i = 0; i < 16; ++i) bm[i] = 0xFFFFFFFFu;
    unsigned cand = (unsigned)col;

    const short8* bl = ((const short8*)bbuf) + l;

    auto kt_body = [&](int kt, short8 b0, short8 b1) {
        float ev = lesq[kt * 16 + col];
        float4v c0 = {ev, ev, ev, ev};
        #pragma unroll
        for (int mt = 0; mt < 4; ++mt) {
            float4v acc = __builtin_amdgcn_mfma_f32_16x16x32_bf16(a[mt][0], b0, c0, 0, 0, 0);
            acc = __builtin_amdgcn_mfma_f32_16x16x32_bf16(a[mt][1], b1, acc, 0, 0, 0);
            #pragma unroll
            for (int r = 0; r < 4; ++r) {
                unsigned pk = (__builtin_bit_cast(unsigned, acc[r]) & 0xFFFFFC00u) | cand;
                bm[mt * 4 + r] = umin32(bm[mt * 4 + r], pk);
            }
        }
        cand += 16;
    };

    // depth-2 kt pipeline in named registers (ds_read ~120 cyc covered by ~2x90 cyc issue)
    short8 A0 = bl[0],   A1 = bl[64];
    short8 A2 = bl[128], A3 = bl[192];
    for (int kt = 0; kt < 64; kt += 2) {
        short8 t0 = A0, t1 = A1, t2 = A2, t3 = A3;
        if (kt + 2 < 64) {
            A0 = bl[(kt + 2) * 128];  A1 = bl[(kt + 2) * 128 + 64];
            A2 = bl[(kt + 3) * 128];  A3 = bl[(kt + 3) * 128 + 64];
        }
        kt_body(kt,     t0, t1);
        kt_body(kt + 1, t2, t3);
    }

    // ---- argmin across the 16 code-columns (packed butterfly) ----
    #pragma unroll
    for (int s = 1; s < 16; s <<= 1)
        #pragma unroll
        for (int i = 0; i < 16; ++i) {
            unsigned o = (unsigned)__shfl_xor((int)bm[i], s, 64);
            bm[i] = umin32(bm[i], o);
        }

    // publish indices: point = p0 + mt*16 + q*4 + r
    if (col == 0) {
        #pragma unroll
        for (int mt = 0; mt < 4; ++mt)
            #pragma unroll
            for (int r = 0; r < 4; ++r)
                idxl[p0 + mt * 16 + q * 4 + r] = (int)(bm[mt * 4 + r] & 1023u);
    }

    // ---- loss: wave-exact  Σ x_sq + Σ best(e_sq - 2 dot) ----
    {
        float dsum = 0.0f;
        #pragma unroll
        for (int i = 0; i < 16; ++i)
            dsum += __builtin_bit_cast(float, bm[i] & 0xFFFFFC00u);
        float lp = xs + dsum * 0.0625f - 1.0f;   // /16 col-replication; un-bias
        #pragma unroll
        for (int off = 32; off > 0; off >>= 1) lp += __shfl_down(lp, off, 64);
        if (l == 0) atomicAdd(accum, lp);
    }
    __syncthreads();   // idxl ready; all 8 waves' atomics issued

    // ---- fused final: last block writes the loss ----
    if (t == 0) {
        __threadfence();
        int tk = atomicAdd(cnt, 1);
        if (tk == NBLK - 1) {
            float tot = atomicAdd(accum, 0.0f);
            loss_out[0] = 1.25f * tot * (1.0f / (float)NELM);
        }
    }

    // ---- z_q: gather winning rows in exact fp32 (L2-hot), coalesced strided stores ----
    {
        const float4v* crow = (const float4v*)(cb + (size_t)idxl[t] * CDIM);
        float* zp = zq + (size_t)b * CDIM * HW + hw0 + t;
        #pragma unroll
        for (int i = 0; i < 16; ++i) {
            float4v vv = crow[i];
            zp[(size_t)(i * 4 + 0) * HW] = vv[0];
            zp[(size_t)(i * 4 + 1) * HW] = vv[1];
            zp[(size_t)(i * 4 + 2) * HW] = vv[2];
            zp[(size_t)(i * 4 + 3) * HW] = vv[3];
        }
    }
}

extern "C" void kernel_launch(void* const* d_in, const int* in_sizes, int n_in,
                              void* d_out, int out_size, void* d_ws, size_t ws_size,
                              hipStream_t stream) {
    const float* x  = (const float*)d_in[0];
    const float* cb = (const float*)d_in[1];
    float* esqb  = (float*)d_ws;
    float* accum = esqb + KCB;
    int*   cnt   = (int*)(esqb + KCB + 1);
    unsigned short* cbB = (unsigned short*)(esqb + 2048);
    float* zq   = (float*)d_out;
    float* loss = zq + NELM;

    vq_prep <<<32,   256, 0, stream>>>(cb, esqb, accum, cnt, cbB);
    vq_main <<<NBLK, 512, 0, stream>>>(x, cb, esqb, cbB, zq, accum, cnt, loss);
}

// Round 7
// 113.480 us; speedup vs baseline: 1.2460x; 1.1349x over previous
//
#include <hip/hip_runtime.h>

#define HW    4096
#define CDIM  64
#define KCB   1024
#define NELM  8388608
#define NBLK  256          // one 1024-thread block per CU

typedef __attribute__((ext_vector_type(8))) short  short8;
typedef __attribute__((ext_vector_type(4))) float  float4v;

__device__ inline unsigned short f2bf(float v) {
    unsigned u = __builtin_bit_cast(unsigned, v);
    unsigned r = u + 0x7FFF + ((u >> 16) & 1);   // RNE
    return (unsigned short)(r >> 16);
}
__device__ inline unsigned umin32(unsigned a, unsigned b) { return a < b ? a : b; }

// ws: [0..1023] e_sq+1.0 fp32 | [1024] loss accum | [1025] ticket | [2048..] bf16 -2*cb (B-frag order)
__global__ void vq_prep(const float* __restrict__ cb, float* __restrict__ esqb,
                        float* __restrict__ accum, int* __restrict__ cnt,
                        unsigned short* __restrict__ cbB) {
    int u = blockIdx.x * 256 + threadIdx.x;      // 0..8191
    if (u == 0) { *accum = 0.0f; *cnt = 0; }
    if (u < KCB) {
        const float* row = cb + u * CDIM;
        float s = 0.0f;
        #pragma unroll
        for (int c = 0; c < CDIM; ++c) s = fmaf(row[c], row[c], s);
        esqb[u] = s + 1.0f;                      // +1 bias => packed distances strictly positive
    }
    // B-frag order (R2/R4/R5/R6-verified). B carries -2*e; A carries raw x.
    int k = u >> 3, s7 = u & 7;
    const float* src = cb + k * CDIM + s7 * 8;
    unsigned short tmp[8];
    #pragma unroll
    for (int j = 0; j < 8; ++j) tmp[j] = f2bf(-2.0f * src[j]);
    int kt = k >> 4, n = k & 15, f = s7 >> 2, q = s7 & 3;
    int dst = (((kt * 2 + f) * 64) + q * 16 + n) * 8;
    *(short8*)(cbB + dst) = *(short8*)tmp;
}

__global__ __launch_bounds__(1024, 4)   // 16 waves/CU, VGPR cap 128
void vq_main(const float* __restrict__ x,
             const float* __restrict__ cb,
             const float* __restrict__ esqb,
             const unsigned short* __restrict__ cbB,
             float* __restrict__ zq,
             float* __restrict__ accum,
             int* __restrict__ cnt,
             float* __restrict__ loss_out) {
    // Overlay: bbuf (128 KB, k-loop) and zbuf (64*513*4 = 128.25 KB, epilogue) share smem.
    __shared__ __align__(16) unsigned char smem[131328];
    __shared__ float lesq[KCB];      // 4 KB
    __shared__ int   idxl[512];      // 2 KB
    __shared__ float wred[16];
    unsigned short* bbuf = (unsigned short*)smem;
    float*          zbuf = (float*)smem;         // [c*513 + pt], stride 513 -> conflict-free

    const int t   = threadIdx.x;                 // 0..1023, 16 waves
    const int n0  = blockIdx.x * 512;            // 512 points per block
    const int b   = n0 >> 12;
    const int hw0 = n0 & (HW - 1);
    const int l   = t & 63, w = t >> 6;
    const int col = l & 15, q = l >> 4;
    const int p0  = w * 32;                      // wave's 32 points

    // ---- stage codebook into LDS: 8 rounds x 1024 threads x 16 B ----
    #pragma unroll
    for (int i = 0; i < 8; ++i) {
        int off = (i * 1024 + t) * 8;            // shorts
        __builtin_amdgcn_global_load_lds(
            (const __attribute__((address_space(1))) unsigned int*)(cbB + off),
            (__attribute__((address_space(3))) unsigned int*)(&bbuf[off]),
            16, 0, 0);
    }
    lesq[t] = esqb[t];

    // ---- A fragments direct from global (overlaps staging): 32 pts/wave ----
    short8 a[2][2];
    float  xs = 0.0f;
    const float* xbase = x + (size_t)b * CDIM * HW + hw0;
    #pragma unroll
    for (int mt = 0; mt < 2; ++mt) {
        const int p = p0 + mt * 16 + col;
        #pragma unroll
        for (int f = 0; f < 2; ++f) {
            unsigned short tmp[8];
            #pragma unroll
            for (int j = 0; j < 8; ++j) {
                float v = xbase[(size_t)(f * 32 + q * 8 + j) * HW + p];
                xs = fmaf(v, v, xs);
                tmp[j] = f2bf(v);
            }
            a[mt][f] = *(short8*)tmp;
        }
    }
    __syncthreads();   // bbuf + lesq resident

    // ---- k-loop: B from LDS; acc = (1+e_sq) + x·(-2e); packed argmin ----
    unsigned bm[8];
    #pragma unroll
    for (int i = 0; i < 8; ++i) bm[i] = 0xFFFFFFFFu;
    unsigned cand = (unsigned)col;
    const short8* bl = ((const short8*)bbuf) + l;

    auto kt_body = [&](int kt, short8 b0, short8 b1) {
        float ev = lesq[kt * 16 + col];
        float4v c0 = {ev, ev, ev, ev};
        #pragma unroll
        for (int mt = 0; mt < 2; ++mt) {
            float4v acc = __builtin_amdgcn_mfma_f32_16x16x32_bf16(a[mt][0], b0, c0, 0, 0, 0);
            acc = __builtin_amdgcn_mfma_f32_16x16x32_bf16(a[mt][1], b1, acc, 0, 0, 0);
            #pragma unroll
            for (int r = 0; r < 4; ++r) {
                unsigned pk = (__builtin_bit_cast(unsigned, acc[r]) & 0xFFFFFC00u) | cand;
                bm[mt * 4 + r] = umin32(bm[mt * 4 + r], pk);
            }
        }
        cand += 16;
    };

    short8 A0 = bl[0],   A1 = bl[64];
    short8 A2 = bl[128], A3 = bl[192];
    for (int kt = 0; kt < 64; kt += 2) {
        short8 t0 = A0, t1 = A1, t2 = A2, t3 = A3;
        if (kt + 2 < 64) {
            A0 = bl[(kt + 2) * 128];  A1 = bl[(kt + 2) * 128 + 64];
            A2 = bl[(kt + 3) * 128];  A3 = bl[(kt + 3) * 128 + 64];
        }
        kt_body(kt,     t0, t1);
        kt_body(kt + 1, t2, t3);
    }

    // ---- argmin across the 16 code-columns (packed butterfly) ----
    #pragma unroll
    for (int s = 1; s < 16; s <<= 1)
        #pragma unroll
        for (int i = 0; i < 8; ++i) {
            unsigned o = (unsigned)__shfl_xor((int)bm[i], s, 64);
            bm[i] = umin32(bm[i], o);
        }

    // publish indices: point = p0 + mt*16 + q*4 + r
    if (col == 0) {
        #pragma unroll
        for (int mt = 0; mt < 2; ++mt)
            #pragma unroll
            for (int r = 0; r < 4; ++r)
                idxl[p0 + mt * 16 + q * 4 + r] = (int)(bm[mt * 4 + r] & 1023u);
    }

    // ---- loss partial: Σ x_sq + Σ best(e_sq - 2 dot) over wave's 32 pts ----
    {
        float dsum = 0.0f;
        #pragma unroll
        for (int i = 0; i < 8; ++i)
            dsum += __builtin_bit_cast(float, bm[i] & 0xFFFFFC00u);
        float lp = xs + dsum * 0.0625f - 0.5f;   // /16 col-replication; un-bias 32 pts / 64 lanes
        #pragma unroll
        for (int off = 32; off > 0; off >>= 1) lp += __shfl_down(lp, off, 64);
        if (l == 0) wred[w] = lp;
    }
    __syncthreads();   // bbuf dead, idxl + wred ready

    if (t == 0) {
        float s = 0.0f;
        #pragma unroll
        for (int i = 0; i < 16; ++i) s += wred[i];
        atomicAdd(accum, s);
    }

    // ---- phase 1: cooperative gather of winning rows -> zbuf (channel-major) ----
    #pragma unroll
    for (int i = 0; i < 8; ++i) {
        int g  = i * 1024 + t;                   // float4 unit: 512 pts x 16
        int pt = g >> 4, sg = g & 15;
        const float4v vv = *(const float4v*)(cb + (size_t)idxl[pt] * CDIM + sg * 4);
        #pragma unroll
        for (int j = 0; j < 4; ++j) zbuf[(sg * 4 + j) * 513 + pt] = vv[j];
    }
    __syncthreads();   // zbuf ready

    // ---- phase 2: coalesced z_q stores from zbuf ----
    {
        const int pt = t & 511, ch = t >> 9;     // 32 channels per thread
        float* zp = zq + ((size_t)b * CDIM + ch * 32) * HW + hw0 + pt;
        #pragma unroll
        for (int c = 0; c < 32; ++c)
            zp[(size_t)c * HW] = zbuf[(ch * 32 + c) * 513 + pt];
    }

    // ---- fused final: last block writes the loss ----
    if (t == 0) {
        __threadfence();
        int tk = atomicAdd(cnt, 1);
        if (tk == NBLK - 1) {
            float tot = atomicAdd(accum, 0.0f);
            loss_out[0] = 1.25f * tot * (1.0f / (float)NELM);
        }
    }
}

extern "C" void kernel_launch(void* const* d_in, const int* in_sizes, int n_in,
                              void* d_out, int out_size, void* d_ws, size_t ws_size,
                              hipStream_t stream) {
    const float* x  = (const float*)d_in[0];
    const float* cb = (const float*)d_in[1];
    float* esqb  = (float*)d_ws;
    float* accum = esqb + KCB;
    int*   cnt   = (int*)(esqb + KCB + 1);
    unsigned short* cbB = (unsigned short*)(esqb + 2048);
    float* zq   = (float*)d_out;
    float* loss = zq + NELM;

    vq_prep <<<32,   256,  0, stream>>>(cb, esqb, accum, cnt, cbB);
    vq_main <<<NBLK, 1024, 0, stream>>>(x, cb, esqb, cbB, zq, accum, cnt, loss);
}